// Round 4
// baseline (632.746 us; speedup 1.0000x reference)
//
#include <hip/hip_runtime.h>
#include <math.h>

#define IMG_H 2048
#define IMG_W 2048
#define TILE  64
#define NBX   (IMG_W / TILE)
#define NBY   (IMG_H / TILE)
#define STR   72   // LDS row stride in floats (288 B, 16B-aligned)

// NUMERICS ARE LOAD-BEARING (lesson from V2 fail, absmax=4.69 = NMS flip):
// the np reference is bit-matched by V1's exact fp64 expression trees with
// their exact evaluation order. fp64 9-term sums are NOT order-free (exponent
// spread + Sobel cancellation) -> any reassociation risks 1-ulp fp32 changes
// -> NMS near-tie flips. V3 therefore keeps V1's per-pixel arithmetic
// verbatim (same source expression shape => same contraction => same bits)
// inside V2's performance structure (4px/thread, float4 LDS/global IO,
// interior-block fast path). Structure changes only how values are moved,
// never how they are computed.
//
// Local coordinate map (per block): buf_a col k <-> global col xa+k, xa=bx*64-4
//   input rows ly=0..69  <-> global row ya+ly, ya = by*64-3
//   smoothed buf_s[sr][sc] <-> global (ya+1+sr, xa+sc+2), sr=0..67, sc=0..67
//   edges   buf_a[er][ec] <-> global (ya+2+er, xa+ec+3), er=0..65, ec=0..65 valid
//   output  (by*64+orow, bx*64+oc), orow 0..63, oc 0..63
// Out-of-image edge positions are written but provably never read by NMS.

__global__ __launch_bounds__(256, 4) void edge_kernel(const float* __restrict__ img,
                                                      float* __restrict__ out) {
    __shared__ float buf_a[70 * STR];  // input tile; later reused for edges
    __shared__ float buf_s[68 * STR];  // smoothed tile (fp32 per-stage rounding)

    const int tid = threadIdx.x;
    const int bx = blockIdx.x, by = blockIdx.y, n = blockIdx.z;
    const int xa = bx * TILE - 4;      // global col of buf_a col 0 (16B aligned)
    const int ya = by * TILE - 3;      // global row of buf_a row 0
    const float* __restrict__ imgN = img + (size_t)n * (IMG_H * IMG_W);
    float* __restrict__ outN = out + (size_t)n * (IMG_H * IMG_W);
    const bool interior = (bx > 0) & (bx < NBX - 1) & (by > 0) & (by < NBY - 1);

    // ---- stage 1: load 70 rows x 72 cols into buf_a (zero outside image) ----
    if (bx > 0 && bx < NBX - 1) {
        // all 72 cols in-image; only rows can be OOB. 18 float4 per row.
        for (int g = tid; g < 70 * 18; g += 256) {
            int r = g / 18, c = g - r * 18;
            int gy = ya + r;
            float4 v = make_float4(0.f, 0.f, 0.f, 0.f);
            if ((unsigned)gy < IMG_H)
                v = *reinterpret_cast<const float4*>(&imgN[(size_t)gy * IMG_W + (xa + 4 * c)]);
            *reinterpret_cast<float4*>(&buf_a[r * STR + 4 * c]) = v;
        }
    } else {
        // edge-x blocks (bx==0 or 31): scalar with full bounds checks
        for (int g = tid; g < 70 * 72; g += 256) {
            int r = g / 72, k = g - r * 72;
            int gy = ya + r, gx = xa + k;
            float v = 0.f;
            if ((unsigned)gy < IMG_H && (unsigned)gx < IMG_W)
                v = imgN[(size_t)gy * IMG_W + gx];
            buf_a[r * STR + k] = v;
        }
    }
    __syncthreads();

    // ---- stage 2: Gaussian 3x3 — V1's exact fp64 chain per pixel ----
    // vf[j] centered at buf_a col sc0+j+2; taps cols sc0+j+1 .. sc0+j+3
    for (int g = tid; g < 68 * 17; g += 256) {
        int sr = g / 17, c = g - sr * 17;
        int sc0 = 4 * c;
        float r0[8] __attribute__((aligned(16)));
        float r1[8] __attribute__((aligned(16)));
        float r2[8] __attribute__((aligned(16)));
        const float* b0 = &buf_a[sr * STR + sc0];
        const float* b1 = &buf_a[(sr + 1) * STR + sc0];
        const float* b2 = &buf_a[(sr + 2) * STR + sc0];
        *(float4*)&r0[0] = *(const float4*)&b0[0]; *(float4*)&r0[4] = *(const float4*)&b0[4];
        *(float4*)&r1[0] = *(const float4*)&b1[0]; *(float4*)&r1[4] = *(const float4*)&b1[4];
        *(float4*)&r2[0] = *(const float4*)&b2[0]; *(float4*)&r2[4] = *(const float4*)&b2[4];
        float vf[4] __attribute__((aligned(16)));
#pragma unroll
        for (int j = 0; j < 4; ++j) {
            // EXACT V1 expression: same taps, same weights, same left-to-right
            // association (top row, mid row, bottom row).
            double v = 0.0625 * (double)r0[j + 1]
                     + 0.125  * (double)r0[j + 2]
                     + 0.0625 * (double)r0[j + 3]
                     + 0.125  * (double)r1[j + 1]
                     + 0.25   * (double)r1[j + 2]
                     + 0.125  * (double)r1[j + 3]
                     + 0.0625 * (double)r2[j + 1]
                     + 0.125  * (double)r2[j + 2]
                     + 0.0625 * (double)r2[j + 3];
            vf[j] = (float)v;   // single per-stage fp32 rounding
        }
        if (!interior) {
            int gy = ya + 1 + sr;          // global row of this smoothed row
            int gx0 = xa + 2 + sc0;        // global col of vf[0]
            bool rowok = (unsigned)gy < IMG_H;
#pragma unroll
            for (int j = 0; j < 4; ++j)
                if (!(rowok && (unsigned)(gx0 + j) < IMG_W)) vf[j] = 0.f;
        }
        *reinterpret_cast<float4*>(&buf_s[sr * STR + sc0]) = *(const float4*)vf;
    }
    __syncthreads();

    // ---- stage 3: Sobel — V1's exact fp64 expressions, fp32 magnitude ----
    // vf[j] centered at buf_s col ec0+j+1; taps cols ec0+j .. ec0+j+2.
    // cols 66,67 of the edge layer use uninitialized buf_s cols 68,69:
    // garbage, but provably never read by stage 4 (max e-col read = 65).
    for (int g = tid; g < 66 * 17; g += 256) {
        int er = g / 17, c = g - er * 17;
        int ec0 = 4 * c;
        float r0[8] __attribute__((aligned(16)));
        float r1[8] __attribute__((aligned(16)));
        float r2[8] __attribute__((aligned(16)));
        const float* b0 = &buf_s[er * STR + ec0];
        const float* b1 = &buf_s[(er + 1) * STR + ec0];
        const float* b2 = &buf_s[(er + 2) * STR + ec0];
        *(float4*)&r0[0] = *(const float4*)&b0[0]; *(float4*)&r0[4] = *(const float4*)&b0[4];
        *(float4*)&r1[0] = *(const float4*)&b1[0]; *(float4*)&r1[4] = *(const float4*)&b1[4];
        *(float4*)&r2[0] = *(const float4*)&b2[0]; *(float4*)&r2[4] = *(const float4*)&b2[4];
        float vf[4] __attribute__((aligned(16)));
#pragma unroll
        for (int j = 0; j < 4; ++j) {
            // EXACT V1 expressions: a=TL b=T d=TR e=L f=R g=BL h=B p=BR
            double a = (double)r0[j],     b = (double)r0[j + 1], d = (double)r0[j + 2];
            double e = (double)r1[j],                            f = (double)r1[j + 2];
            double gg = (double)r2[j],    h = (double)r2[j + 1], p = (double)r2[j + 2];
            double gxd = (d - a) + 2.0 * (f - e) + (p - gg);
            double gyd = (gg - a) + 2.0 * (h - b) + (p - d);
            float gxf = (float)gxd;          // per-stage fp32 rounding of gx
            float gyf = (float)gyd;          // and gy
            float m2 = __fadd_rn(__fmul_rn(gxf, gxf), __fmul_rn(gyf, gyf));
            vf[j] = (float)sqrt((double)m2); // correctly-rounded fp32 sqrt
        }
        *reinterpret_cast<float4*>(&buf_a[er * STR + ec0]) = *(const float4*)vf;
    }
    __syncthreads();

    // ---- stage 4: NMS (interior px only, exact fp32 compare) + float4 store ----
    for (int g = tid; g < 64 * 16; g += 256) {
        int orow = g >> 4;
        int oc0 = (g & 15) * 4;
        float r0[8] __attribute__((aligned(16)));
        float r1[8] __attribute__((aligned(16)));
        float r2[8] __attribute__((aligned(16)));
        const float* b0 = &buf_a[orow * STR + oc0];
        const float* b1 = &buf_a[(orow + 1) * STR + oc0];
        const float* b2 = &buf_a[(orow + 2) * STR + oc0];
        *(float4*)&r0[0] = *(const float4*)&b0[0]; *(float4*)&r0[4] = *(const float4*)&b0[4];
        *(float4*)&r1[0] = *(const float4*)&b1[0]; *(float4*)&r1[4] = *(const float4*)&b1[4];
        *(float4*)&r2[0] = *(const float4*)&b2[0]; *(float4*)&r2[4] = *(const float4*)&b2[4];
        float vf[4] __attribute__((aligned(16)));
#pragma unroll
        for (int j = 0; j < 4; ++j) {
            float cen = r1[j + 1];
            float m = fmaxf(fmaxf(fmaxf(r0[j], r0[j + 1]), fmaxf(r0[j + 2], r1[j])),
                            fmaxf(fmaxf(r1[j + 2], r2[j]), fmaxf(r2[j + 1], r2[j + 2])));
            vf[j] = (cen < m) ? 0.f : cen;
        }
        int gy = by * TILE + orow;
        int gx0 = bx * TILE + oc0;
        if (!interior) {
            bool rowborder = (gy == 0) | (gy == IMG_H - 1);
#pragma unroll
            for (int j = 0; j < 4; ++j) {
                int gx = gx0 + j;
                if (rowborder | (gx == 0) | (gx == IMG_W - 1)) vf[j] = r1[j + 1];
            }
        }
        *reinterpret_cast<float4*>(&outN[(size_t)gy * IMG_W + gx0]) = *(const float4*)vf;
    }
}

extern "C" void kernel_launch(void* const* d_in, const int* in_sizes, int n_in,
                              void* d_out, int out_size, void* d_ws, size_t ws_size,
                              hipStream_t stream) {
    const float* img = (const float*)d_in[0];
    float* out = (float*)d_out;
    dim3 grid(NBX, NBY, 16);
    edge_kernel<<<grid, dim3(256), 0, stream>>>(img, out);
}

// Round 12
// 568.616 us; speedup vs baseline: 1.1128x; 1.1128x over previous
//
#include <hip/hip_runtime.h>
#include <math.h>

#define IMG_H 2048
#define IMG_W 2048
#define TILE_X 64
#define TILE_Y 32
#define NBX   (IMG_W / TILE_X)   // 32
#define NBY   (IMG_H / TILE_Y)   // 64
#define STR   72   // LDS row stride in floats (288 B, 16B-aligned)

// NUMERICS ARE LOAD-BEARING (V2 fail absmax=4.69; V5 fail absmax=2.52; V3
// pass absmax=0.03125): the np reference is matched by V1's exact fp64
// expression trees in their exact evaluation order, with magnitude =
// (float)sqrt((double)m2). Two hard-won pitfalls:
//   1. fp64 tap-sum reassociation (separable forms) changes fp32 stage bits
//      -> NMS tie flips (V2).
//   2. __fsqrt_rn(m2) is NOT bit-identical to (float)sqrt((double)m2) on
//      this toolchain (V5, absmax 2.52) despite the double-rounding theorem
//      -> its impl is not correctly-rounded fp32 sqrt. NEVER substitute.
// V6 = V4 exactly: verified-V3 arithmetic byte-for-byte, ONLY tile geometry
//   64x64 -> 64x32 (LDS 39936->21312 B, 4->7 blocks/CU, 16->28 waves/CU) to
//   overlap VALU (47.6% busy, V3 meas.) with LDS pipe (~25-30% busy; the
//   4.7e7 SQ_LDS_BANK_CONFLICT cycles are inherent wave64-b128 bank
//   serialization, not fixable conflicts).
// CANARY: per-pixel values are block-boundary-independent, so a passing run
//   must show absmax EXACTLY 0.03125 (same bits as V3). Any other value =>
//   geometry audit wrong => bisect vs V3.
//
// Local coordinate map (per block): buf_a col k <-> global col xa+k, xa=bx*64-4
//   input rows ly=0..37  <-> global row ya+ly, ya = by*32-3
//   smoothed buf_s[sr][sc] <-> global (ya+1+sr, xa+sc+2), sr=0..35, sc=0..67
//   edges   buf_a[er][ec] <-> global (ya+2+er, xa+ec+3), er=0..33, ec=0..65 valid
//   output  (by*32+orow, bx*64+oc), orow 0..31, oc 0..63
// Edge cols 66,67 are garbage (read uninit buf_s cols 68,69) but provably
// never read by stage 4 (max e-col read = 65). Out-of-image edge positions
// are written but never read by NMS (border rows/cols take the passthrough).

__global__ __launch_bounds__(256, 7) void edge_kernel(const float* __restrict__ img,
                                                      float* __restrict__ out) {
    __shared__ float buf_a[38 * STR];  // input tile; later reused for edges
    __shared__ float buf_s[36 * STR];  // smoothed tile (fp32 per-stage rounding)

    const int tid = threadIdx.x;
    const int bx = blockIdx.x, by = blockIdx.y, n = blockIdx.z;
    const int xa = bx * TILE_X - 4;    // global col of buf_a col 0 (16B aligned)
    const int ya = by * TILE_Y - 3;    // global row of buf_a row 0
    const float* __restrict__ imgN = img + (size_t)n * (IMG_H * IMG_W);
    float* __restrict__ outN = out + (size_t)n * (IMG_H * IMG_W);
    const bool interior = (bx > 0) & (bx < NBX - 1) & (by > 0) & (by < NBY - 1);

    // ---- stage 1: load 38 rows x 72 cols into buf_a (zero outside image) ----
    if (bx > 0 && bx < NBX - 1) {
        // all 72 cols in-image; only rows can be OOB. 18 float4 per row.
        for (int g = tid; g < 38 * 18; g += 256) {
            int r = g / 18, c = g - r * 18;
            int gy = ya + r;
            float4 v = make_float4(0.f, 0.f, 0.f, 0.f);
            if ((unsigned)gy < IMG_H)
                v = *reinterpret_cast<const float4*>(&imgN[(size_t)gy * IMG_W + (xa + 4 * c)]);
            *reinterpret_cast<float4*>(&buf_a[r * STR + 4 * c]) = v;
        }
    } else {
        // edge-x blocks (bx==0 or 31): scalar with full bounds checks
        for (int g = tid; g < 38 * 72; g += 256) {
            int r = g / 72, k = g - r * 72;
            int gy = ya + r, gx = xa + k;
            float v = 0.f;
            if ((unsigned)gy < IMG_H && (unsigned)gx < IMG_W)
                v = imgN[(size_t)gy * IMG_W + gx];
            buf_a[r * STR + k] = v;
        }
    }
    __syncthreads();

    // ---- stage 2: Gaussian 3x3 — V1's exact fp64 chain per pixel ----
    // vf[j] centered at buf_a col sc0+j+2; taps cols sc0+j+1 .. sc0+j+3
    for (int g = tid; g < 36 * 17; g += 256) {
        int sr = g / 17, c = g - sr * 17;
        int sc0 = 4 * c;
        float r0[8] __attribute__((aligned(16)));
        float r1[8] __attribute__((aligned(16)));
        float r2[8] __attribute__((aligned(16)));
        const float* b0 = &buf_a[sr * STR + sc0];
        const float* b1 = &buf_a[(sr + 1) * STR + sc0];
        const float* b2 = &buf_a[(sr + 2) * STR + sc0];
        *(float4*)&r0[0] = *(const float4*)&b0[0]; *(float4*)&r0[4] = *(const float4*)&b0[4];
        *(float4*)&r1[0] = *(const float4*)&b1[0]; *(float4*)&r1[4] = *(const float4*)&b1[4];
        *(float4*)&r2[0] = *(const float4*)&b2[0]; *(float4*)&r2[4] = *(const float4*)&b2[4];
        float vf[4] __attribute__((aligned(16)));
#pragma unroll
        for (int j = 0; j < 4; ++j) {
            // EXACT V1 expression: same taps, same weights, same left-to-right
            // association (top row, mid row, bottom row).
            double v = 0.0625 * (double)r0[j + 1]
                     + 0.125  * (double)r0[j + 2]
                     + 0.0625 * (double)r0[j + 3]
                     + 0.125  * (double)r1[j + 1]
                     + 0.25   * (double)r1[j + 2]
                     + 0.125  * (double)r1[j + 3]
                     + 0.0625 * (double)r2[j + 1]
                     + 0.125  * (double)r2[j + 2]
                     + 0.0625 * (double)r2[j + 3];
            vf[j] = (float)v;   // single per-stage fp32 rounding
        }
        if (!interior) {
            int gy = ya + 1 + sr;          // global row of this smoothed row
            int gx0 = xa + 2 + sc0;        // global col of vf[0]
            bool rowok = (unsigned)gy < IMG_H;
#pragma unroll
            for (int j = 0; j < 4; ++j)
                if (!(rowok && (unsigned)(gx0 + j) < IMG_W)) vf[j] = 0.f;
        }
        *reinterpret_cast<float4*>(&buf_s[sr * STR + sc0]) = *(const float4*)vf;
    }
    __syncthreads();

    // ---- stage 3: Sobel — V1's exact fp64 expressions, fp32 magnitude ----
    // vf[j] centered at buf_s col ec0+j+1; taps cols ec0+j .. ec0+j+2.
    for (int g = tid; g < 34 * 17; g += 256) {
        int er = g / 17, c = g - er * 17;
        int ec0 = 4 * c;
        float r0[8] __attribute__((aligned(16)));
        float r1[8] __attribute__((aligned(16)));
        float r2[8] __attribute__((aligned(16)));
        const float* b0 = &buf_s[er * STR + ec0];
        const float* b1 = &buf_s[(er + 1) * STR + ec0];
        const float* b2 = &buf_s[(er + 2) * STR + ec0];
        *(float4*)&r0[0] = *(const float4*)&b0[0]; *(float4*)&r0[4] = *(const float4*)&b0[4];
        *(float4*)&r1[0] = *(const float4*)&b1[0]; *(float4*)&r1[4] = *(const float4*)&b1[4];
        *(float4*)&r2[0] = *(const float4*)&b2[0]; *(float4*)&r2[4] = *(const float4*)&b2[4];
        float vf[4] __attribute__((aligned(16)));
#pragma unroll
        for (int j = 0; j < 4; ++j) {
            // EXACT V1 expressions: a=TL b=T d=TR e=L f=R g=BL h=B p=BR
            double a = (double)r0[j],     b = (double)r0[j + 1], d = (double)r0[j + 2];
            double e = (double)r1[j],                            f = (double)r1[j + 2];
            double gg = (double)r2[j],    h = (double)r2[j + 1], p = (double)r2[j + 2];
            double gxd = (d - a) + 2.0 * (f - e) + (p - gg);
            double gyd = (gg - a) + 2.0 * (h - b) + (p - d);
            float gxf = (float)gxd;          // per-stage fp32 rounding of gx
            float gyf = (float)gyd;          // and gy
            float m2 = __fadd_rn(__fmul_rn(gxf, gxf), __fmul_rn(gyf, gyf));
            // PITFALL (V5): __fsqrt_rn(m2) here FAILED verification
            // (absmax 2.52, NMS tie flips) -> not correctly-rounded on this
            // toolchain. Keep the fp64 path verbatim.
            vf[j] = (float)sqrt((double)m2); // correctly-rounded fp32 sqrt
        }
        *reinterpret_cast<float4*>(&buf_a[er * STR + ec0]) = *(const float4*)vf;
    }
    __syncthreads();

    // ---- stage 4: NMS (interior px only, exact fp32 compare) + float4 store ----
    for (int g = tid; g < 32 * 16; g += 256) {
        int orow = g >> 4;
        int oc0 = (g & 15) * 4;
        float r0[8] __attribute__((aligned(16)));
        float r1[8] __attribute__((aligned(16)));
        float r2[8] __attribute__((aligned(16)));
        const float* b0 = &buf_a[orow * STR + oc0];
        const float* b1 = &buf_a[(orow + 1) * STR + oc0];
        const float* b2 = &buf_a[(orow + 2) * STR + oc0];
        *(float4*)&r0[0] = *(const float4*)&b0[0]; *(float4*)&r0[4] = *(const float4*)&b0[4];
        *(float4*)&r1[0] = *(const float4*)&b1[0]; *(float4*)&r1[4] = *(const float4*)&b1[4];
        *(float4*)&r2[0] = *(const float4*)&b2[0]; *(float4*)&r2[4] = *(const float4*)&b2[4];
        float vf[4] __attribute__((aligned(16)));
#pragma unroll
        for (int j = 0; j < 4; ++j) {
            float cen = r1[j + 1];
            float m = fmaxf(fmaxf(fmaxf(r0[j], r0[j + 1]), fmaxf(r0[j + 2], r1[j])),
                            fmaxf(fmaxf(r1[j + 2], r2[j]), fmaxf(r2[j + 1], r2[j + 2])));
            vf[j] = (cen < m) ? 0.f : cen;
        }
        int gy = by * TILE_Y + orow;
        int gx0 = bx * TILE_X + oc0;
        if (!interior) {
            bool rowborder = (gy == 0) | (gy == IMG_H - 1);
#pragma unroll
            for (int j = 0; j < 4; ++j) {
                int gx = gx0 + j;
                if (rowborder | (gx == 0) | (gx == IMG_W - 1)) vf[j] = r1[j + 1];
            }
        }
        *reinterpret_cast<float4*>(&outN[(size_t)gy * IMG_W + gx0]) = *(const float4*)vf;
    }
}

extern "C" void kernel_launch(void* const* d_in, const int* in_sizes, int n_in,
                              void* d_out, int out_size, void* d_ws, size_t ws_size,
                              hipStream_t stream) {
    const float* img = (const float*)d_in[0];
    float* out = (float*)d_out;
    dim3 grid(NBX, NBY, 16);
    edge_kernel<<<grid, dim3(256), 0, stream>>>(img, out);
}

// Round 14
// 549.387 us; speedup vs baseline: 1.1517x; 1.0350x over previous
//
#include <hip/hip_runtime.h>
#include <math.h>

#define IMG_H 2048
#define IMG_W 2048
#define TILE_X 64
#define TILE_Y 32
#define NBX   (IMG_W / TILE_X)   // 32
#define NBY   (IMG_H / TILE_Y)   // 64
#define STR   72   // LDS row stride in floats (288 B, 16B-aligned)

// NUMERICS ARE LOAD-BEARING (V2 fail 4.69; V5 fail 2.52; V3/V6 pass with
// absmax EXACTLY 0.03125): the np reference is matched by V1's exact fp64
// expression trees in their exact evaluation order, magnitude =
// (float)sqrt((double)m2). Pitfalls (never retry):
//   1. fp64 tap-sum reassociation (separable forms) -> NMS tie flips (V2).
//   2. __fsqrt_rn(m2) is NOT bit-identical to (float)sqrt((double)m2) on
//      this toolchain (V5) -> not correctly-rounded. Keep fp64 sqrt.
// V6 measured: 289 us/dispatch, VALU 63.6%, occ 55.7%, conflicts 4.92e7,
//   FETCH 258MB (halo re-reads L2-absorbed).
// V7 (this): pure data-movement refactor -- vertical strip blocking with a
//   register sliding window. Stages 2-3: 12 strips(3 rows) x 17 colgroups =
//   204 threads, 12 px each (same critical-wave px as V6, but rows shared:
//   wave-b128 189->126/block, cvts -40% via CSE of identical SSA values,
//   iterations 1702->664). Stage 4: 16 strips(2 rows) x 16 cg = 256 exact.
//   ALL value-producing expressions are verbatim V6 (macros). cvt hoisting
//   and load sharing are exact; no reassociation anywhere.
// CANARY: pass must show absmax EXACTLY 0.03125; anything else = refactor
//   bug (values are block/thread-partition independent).
//
// Coordinate map (per block): buf_a col k <-> global col xa+k, xa=bx*64-4
//   input rows 0..37 <-> global ya+r, ya = by*32-3
//   smoothed buf_s[sr][sc] <-> (ya+1+sr, xa+sc+2), sr=0..35, sc=0..67
//   edges   buf_a[er][ec] <-> (ya+2+er, xa+ec+3), er=0..33, ec=0..65 valid
//   output  (by*32+orow, bx*64+oc), orow=0..31, oc=0..63
// Edge cols 66,67 garbage (from uninit buf_s 68,69), never read by NMS
// (max e-col read 65). Out-of-image edge values never read (passthrough).

#define LD8A(DST, ROW, C0) do { \
    *(float4*)&DST[0] = *(const float4*)&buf_a[(ROW) * STR + (C0)]; \
    *(float4*)&DST[4] = *(const float4*)&buf_a[(ROW) * STR + (C0) + 4]; \
} while (0)

#define LD8S(DST, ROW, C0) do { \
    *(float4*)&DST[0] = *(const float4*)&buf_s[(ROW) * STR + (C0)]; \
    *(float4*)&DST[4] = *(const float4*)&buf_s[(ROW) * STR + (C0) + 4]; \
} while (0)

// Gaussian row: EXACT V6 tree (left-assoc chain, same tap order/weights).
#define GROW(RT, RM, RB, SR_) do { \
    float vf[4] __attribute__((aligned(16))); \
    _Pragma("unroll") \
    for (int j = 0; j < 4; ++j) { \
        double v = 0.0625 * (double)RT[j + 1] \
                 + 0.125  * (double)RT[j + 2] \
                 + 0.0625 * (double)RT[j + 3] \
                 + 0.125  * (double)RM[j + 1] \
                 + 0.25   * (double)RM[j + 2] \
                 + 0.125  * (double)RM[j + 3] \
                 + 0.0625 * (double)RB[j + 1] \
                 + 0.125  * (double)RB[j + 2] \
                 + 0.0625 * (double)RB[j + 3]; \
        vf[j] = (float)v; \
    } \
    if (!interior) { \
        int gy = ya + 1 + (SR_); \
        int gx0 = xa + 2 + sc0; \
        bool rowok = (unsigned)gy < IMG_H; \
        _Pragma("unroll") \
        for (int j = 0; j < 4; ++j) \
            if (!(rowok && (unsigned)(gx0 + j) < IMG_W)) vf[j] = 0.f; \
    } \
    *(float4*)&buf_s[(SR_) * STR + sc0] = *(const float4*)vf; \
} while (0)

// Sobel row: EXACT V6 expressions + fp64 sqrt path (PITFALL: keep verbatim).
#define SROW(RT, RM, RB, ER_) do { \
    float vf[4] __attribute__((aligned(16))); \
    _Pragma("unroll") \
    for (int j = 0; j < 4; ++j) { \
        double a = (double)RT[j],  b = (double)RT[j + 1], d = (double)RT[j + 2]; \
        double e = (double)RM[j],                         f = (double)RM[j + 2]; \
        double gg = (double)RB[j], h = (double)RB[j + 1], p = (double)RB[j + 2]; \
        double gxd = (d - a) + 2.0 * (f - e) + (p - gg); \
        double gyd = (gg - a) + 2.0 * (h - b) + (p - d); \
        float gxf = (float)gxd; \
        float gyf = (float)gyd; \
        float m2 = __fadd_rn(__fmul_rn(gxf, gxf), __fmul_rn(gyf, gyf)); \
        vf[j] = (float)sqrt((double)m2); \
    } \
    *(float4*)&buf_a[(ER_) * STR + ec0] = *(const float4*)vf; \
} while (0)

// NMS row: EXACT V6 compare + border passthrough + global float4 store.
#define NMSROW(RT, RM, RB, OROW_) do { \
    float vf[4] __attribute__((aligned(16))); \
    _Pragma("unroll") \
    for (int j = 0; j < 4; ++j) { \
        float cen = RM[j + 1]; \
        float m = fmaxf(fmaxf(fmaxf(RT[j], RT[j + 1]), fmaxf(RT[j + 2], RM[j])), \
                        fmaxf(fmaxf(RM[j + 2], RB[j]), fmaxf(RB[j + 1], RB[j + 2]))); \
        vf[j] = (cen < m) ? 0.f : cen; \
    } \
    int gy = by * TILE_Y + (OROW_); \
    int gx0 = bx * TILE_X + oc0; \
    if (!interior) { \
        bool rowborder = (gy == 0) | (gy == IMG_H - 1); \
        _Pragma("unroll") \
        for (int j = 0; j < 4; ++j) { \
            int gx = gx0 + j; \
            if (rowborder | (gx == 0) | (gx == IMG_W - 1)) vf[j] = RM[j + 1]; \
        } \
    } \
    *reinterpret_cast<float4*>(&outN[(size_t)gy * IMG_W + gx0]) = *(const float4*)vf; \
} while (0)

__global__ __launch_bounds__(256, 7) void edge_kernel(const float* __restrict__ img,
                                                      float* __restrict__ out) {
    __shared__ float buf_a[38 * STR];  // input tile; later reused for edges
    __shared__ float buf_s[36 * STR];  // smoothed tile

    const int tid = threadIdx.x;
    const int bx = blockIdx.x, by = blockIdx.y, n = blockIdx.z;
    const int xa = bx * TILE_X - 4;
    const int ya = by * TILE_Y - 3;
    const float* __restrict__ imgN = img + (size_t)n * (IMG_H * IMG_W);
    float* __restrict__ outN = out + (size_t)n * (IMG_H * IMG_W);
    const bool interior = (bx > 0) & (bx < NBX - 1) & (by > 0) & (by < NBY - 1);

    // ---- stage 1: load 38 rows x 72 cols into buf_a (zero outside) — V6 ----
    if (bx > 0 && bx < NBX - 1) {
        for (int g = tid; g < 38 * 18; g += 256) {
            int r = g / 18, c = g - r * 18;
            int gy = ya + r;
            float4 v = make_float4(0.f, 0.f, 0.f, 0.f);
            if ((unsigned)gy < IMG_H)
                v = *reinterpret_cast<const float4*>(&imgN[(size_t)gy * IMG_W + (xa + 4 * c)]);
            *reinterpret_cast<float4*>(&buf_a[r * STR + 4 * c]) = v;
        }
    } else {
        for (int g = tid; g < 38 * 72; g += 256) {
            int r = g / 72, k = g - r * 72;
            int gy = ya + r, gx = xa + k;
            float v = 0.f;
            if ((unsigned)gy < IMG_H && (unsigned)gx < IMG_W)
                v = imgN[(size_t)gy * IMG_W + gx];
            buf_a[r * STR + k] = v;
        }
    }
    __syncthreads();

    // ---- stage 2: Gaussian, 12 strips(3 rows) x 17 colgroups, sliding window
    if (tid < 204) {
        int s = tid / 17;
        int cg = tid - s * 17;
        int sc0 = 4 * cg;
        int r3 = s * 3;                 // smoothed rows r3..r3+2; input rows r3..r3+4
        float rA[8] __attribute__((aligned(16)));
        float rB[8] __attribute__((aligned(16)));
        float rC[8] __attribute__((aligned(16)));
        LD8A(rA, r3, sc0);
        LD8A(rB, r3 + 1, sc0);
        LD8A(rC, r3 + 2, sc0);  GROW(rA, rB, rC, r3 + 0);
        LD8A(rA, r3 + 3, sc0);  GROW(rB, rC, rA, r3 + 1);
        LD8A(rB, r3 + 4, sc0);  GROW(rC, rA, rB, r3 + 2);
    }
    __syncthreads();

    // ---- stage 3: Sobel, 12 strips (11x3 rows + 1x1) x 17 colgroups --------
    if (tid < 204) {
        int s = tid / 17;
        int cg = tid - s * 17;
        int ec0 = 4 * cg;
        int e3 = s * 3;                 // edge rows e3..e3+R-1; smoothed rows e3..e3+R+1
        bool full = (s < 11);           // s==11: only edge row 33 (R=1)
        float rA[8] __attribute__((aligned(16)));
        float rB[8] __attribute__((aligned(16)));
        float rC[8] __attribute__((aligned(16)));
        LD8S(rA, e3, ec0);
        LD8S(rB, e3 + 1, ec0);
        LD8S(rC, e3 + 2, ec0);  SROW(rA, rB, rC, e3 + 0);
        if (full) {
            LD8S(rA, e3 + 3, ec0);  SROW(rB, rC, rA, e3 + 1);
            LD8S(rB, e3 + 4, ec0);  SROW(rC, rA, rB, e3 + 2);
        }
    }
    __syncthreads();

    // ---- stage 4: NMS, 16 strips(2 rows) x 16 colgroups = 256 threads -----
    {
        int st = tid >> 4;
        int oc0 = (tid & 15) * 4;
        int e0 = st * 2;                // edge rows e0..e0+3 for output rows 2st,2st+1
        float r0[8] __attribute__((aligned(16)));
        float r1[8] __attribute__((aligned(16)));
        float r2[8] __attribute__((aligned(16)));
        float r3v[8] __attribute__((aligned(16)));
        LD8A(r0, e0, oc0);
        LD8A(r1, e0 + 1, oc0);
        LD8A(r2, e0 + 2, oc0);
        LD8A(r3v, e0 + 3, oc0);
        NMSROW(r0, r1, r2, 2 * st + 0);
        NMSROW(r1, r2, r3v, 2 * st + 1);
    }
}

extern "C" void kernel_launch(void* const* d_in, const int* in_sizes, int n_in,
                              void* d_out, int out_size, void* d_ws, size_t ws_size,
                              hipStream_t stream) {
    const float* img = (const float*)d_in[0];
    float* out = (float*)d_out;
    dim3 grid(NBX, NBY, 16);
    edge_kernel<<<grid, dim3(256), 0, stream>>>(img, out);
}